// Round 2
// baseline (1401.707 us; speedup 1.0000x reference)
//
#include <hip/hip_runtime.h>

#define B 32
#define S 2048
#define I 256
#define H 256

typedef _Float16 h2 __attribute__((ext_vector_type(2)));

__device__ __forceinline__ float fdot2(h2 a, h2 b, float c) {
#if __has_builtin(__builtin_amdgcn_fdot2)
    return __builtin_amdgcn_fdot2(a, b, c, false);
#else
    return fmaf((float)a[1], (float)b[1], fmaf((float)a[0], (float)b[0], c));
#endif
}

// lgkm-only workgroup barrier: __syncthreads() drains vmcnt(0) before
// s_barrier; our per-step global ops are thread-private columns so only LDS
// needs cross-wave visibility. imm 0xC07F = vmcnt(63) expcnt(7) lgkmcnt(0).
__device__ __forceinline__ void lds_barrier() {
    __asm__ __volatile__("" ::: "memory");
    __builtin_amdgcn_s_waitcnt(0xC07F);
    __builtin_amdgcn_s_barrier();
    __asm__ __volatile__("" ::: "memory");
}

__device__ __forceinline__ float fast_tanh(float x) {
    float e = __expf(2.0f * x);
    return 1.0f - __fdividef(2.0f, e + 1.0f);
}

// ---------------------------------------------------------------------------
// Phase 1: xw[m][n] = sum_k x[m][k]*Wxw[n][k] + Wxb[n]   (unchanged)
// ---------------------------------------------------------------------------
#define TM 64
#define TN 64
#define TK 32

__global__ __launch_bounds__(256) void phase1_gemm(
    const float* __restrict__ x, const float* __restrict__ Wxw,
    const float* __restrict__ Wxb, float* __restrict__ out)
{
    __shared__ __align__(16) float As[TK][TM + 4];
    __shared__ __align__(16) float Bs[TK][TN + 4];

    const int t  = threadIdx.x;
    const int tn = t & 15, tm = t >> 4;
    const int m0 = blockIdx.x * TM;
    const int n0 = blockIdx.y * TN;

    float acc[4][4] = {};
    float bias[4];
#pragma unroll
    for (int j = 0; j < 4; ++j) bias[j] = Wxb[n0 + 4 * tn + j];

    const int lr = t >> 3;
    const int lc = t & 7;

    for (int kt = 0; kt < I; kt += TK) {
#pragma unroll
        for (int hh = 0; hh < 2; ++hh) {
            const int m = lr + 32 * hh;
            float4 v = *(const float4*)(x   + (size_t)(m0 + m) * I + kt + 4 * lc);
            As[4 * lc + 0][m] = v.x; As[4 * lc + 1][m] = v.y;
            As[4 * lc + 2][m] = v.z; As[4 * lc + 3][m] = v.w;
            float4 w = *(const float4*)(Wxw + (size_t)(n0 + m) * I + kt + 4 * lc);
            Bs[4 * lc + 0][m] = w.x; Bs[4 * lc + 1][m] = w.y;
            Bs[4 * lc + 2][m] = w.z; Bs[4 * lc + 3][m] = w.w;
        }
        __syncthreads();
#pragma unroll
        for (int k = 0; k < TK; ++k) {
            float4 a = *(const float4*)&As[k][4 * tm];
            float4 b = *(const float4*)&Bs[k][4 * tn];
            float av[4] = {a.x, a.y, a.z, a.w};
            float bv[4] = {b.x, b.y, b.z, b.w};
#pragma unroll
            for (int i2 = 0; i2 < 4; ++i2)
#pragma unroll
                for (int j = 0; j < 4; ++j)
                    acc[i2][j] = fmaf(av[i2], bv[j], acc[i2][j]);
        }
        __syncthreads();
    }
#pragma unroll
    for (int i2 = 0; i2 < 4; ++i2) {
        float4 v = { acc[i2][0] + bias[0], acc[i2][1] + bias[1],
                     acc[i2][2] + bias[2], acc[i2][3] + bias[3] };
        *(float4*)(out + (size_t)(m0 + 4 * tm + i2) * H + n0 + 4 * tn) = v;
    }
}

// ---------------------------------------------------------------------------
// Phase 2: h = tanh(xw_s + h @ Whw^T), 2048 steps. 32 blocks x 256 threads.
//
// R5 post-mortem: readlane broadcast regressed (SGPR hazards); fdot2 issues
// at ~4 cyc so VALU floor ~550 cyc/step. R3's remaining ~640 cyc stall was
// the K-split structure: partial-write -> barrier -> pbuf read -> tanh ->
// hsh write -> broadcast read = TWO LDS round trips per step.
//
// R6 structure: thread t owns output ROW t over the FULL K=256.
//   - wreg = W[t][0..255] as 128 h2 VGPRs (full unroll)
//   - MAC: 32 wave-uniform ds_read_b128 of hsh (broadcast, conflict-free),
//     128 fdot2 in 4 independent k-quarter chains
//   - lane has the COMPLETE row sum -> tanh directly: NO cross-wave reduce,
//     no pbuf, no reduce barrier or read latency.
//   - hsh double-buffered: write h(s) to hsh[p^1] while others may still
//     read hsh[p]; ONE lgkm-only barrier per step publishes it.
// Chain/step: bar -> bcast read (~130) -> 128 fdot2 (~510 issue) -> tanh
// -> b16 write -> bar  ==> ~730 cyc vs R3's ~1190.
// ---------------------------------------------------------------------------
__global__ __launch_bounds__(256, 1) void phase2_rnn(
    const float* __restrict__ Whw, float* __restrict__ out)
{
    __shared__ __align__(16) _Float16 hsh[2][H];   // double-buffered h (f16)

    const int b = blockIdx.x;
    const int t = threadIdx.x;

    // wreg[j] = W[t][2j .. 2j+1] as h2, j = 0..127. Constant indices only.
    h2 wreg[128];
#pragma unroll
    for (int q = 0; q < 64; ++q) {
        float4 f = ((const float4*)(Whw + (size_t)t * H))[q];
        wreg[2 * q]     = h2{(_Float16)f.x, (_Float16)f.y};
        wreg[2 * q + 1] = h2{(_Float16)f.z, (_Float16)f.w};
    }

    hsh[0][t] = (_Float16)0.0f;
    __syncthreads();

    // xw column t of batch b, read/written in place in d_out. 2-deep prefetch;
    // reads up to 2 steps past the end land in the h_last region (in bounds,
    // values unused).
    float* outb = out + (size_t)b * S * H + t;
    float*       op = outb;
    const float* lp = outb + 2 * (size_t)H;
    float xw0 = outb[0], xw1 = outb[(size_t)H];

    float hv = 0.f;
    int p = 0;
    for (int s = 0; s < S; ++s) {
        float xwn = lp[0]; lp += H;          // prefetch xw for step s+2

        // MAC: row t x full K. h via wave-uniform b128 broadcast reads.
        // 4 independent accumulation chains (k-quarters) for ILP.
        const uint4* hp = (const uint4*)hsh[p];
        float acc0 = 0.f, acc1 = 0.f, acc2 = 0.f, acc3 = 0.f;
#pragma unroll
        for (int u = 0; u < 8; ++u) {        // uint4 covers 8 h values
            uint4 v0 = hp[u];                // k =   0 + 8u ..
            uint4 v1 = hp[u + 8];            // k =  64 + 8u ..
            uint4 v2 = hp[u + 16];           // k = 128 + 8u ..
            uint4 v3 = hp[u + 24];           // k = 192 + 8u ..
            acc0 = fdot2(wreg[4 * u + 0],      __builtin_bit_cast(h2, v0.x), acc0);
            acc0 = fdot2(wreg[4 * u + 1],      __builtin_bit_cast(h2, v0.y), acc0);
            acc0 = fdot2(wreg[4 * u + 2],      __builtin_bit_cast(h2, v0.z), acc0);
            acc0 = fdot2(wreg[4 * u + 3],      __builtin_bit_cast(h2, v0.w), acc0);
            acc1 = fdot2(wreg[32 + 4 * u + 0], __builtin_bit_cast(h2, v1.x), acc1);
            acc1 = fdot2(wreg[32 + 4 * u + 1], __builtin_bit_cast(h2, v1.y), acc1);
            acc1 = fdot2(wreg[32 + 4 * u + 2], __builtin_bit_cast(h2, v1.z), acc1);
            acc1 = fdot2(wreg[32 + 4 * u + 3], __builtin_bit_cast(h2, v1.w), acc1);
            acc2 = fdot2(wreg[64 + 4 * u + 0], __builtin_bit_cast(h2, v2.x), acc2);
            acc2 = fdot2(wreg[64 + 4 * u + 1], __builtin_bit_cast(h2, v2.y), acc2);
            acc2 = fdot2(wreg[64 + 4 * u + 2], __builtin_bit_cast(h2, v2.z), acc2);
            acc2 = fdot2(wreg[64 + 4 * u + 3], __builtin_bit_cast(h2, v2.w), acc2);
            acc3 = fdot2(wreg[96 + 4 * u + 0], __builtin_bit_cast(h2, v3.x), acc3);
            acc3 = fdot2(wreg[96 + 4 * u + 1], __builtin_bit_cast(h2, v3.y), acc3);
            acc3 = fdot2(wreg[96 + 4 * u + 2], __builtin_bit_cast(h2, v3.z), acc3);
            acc3 = fdot2(wreg[96 + 4 * u + 3], __builtin_bit_cast(h2, v3.w), acc3);
        }
        float sum = (acc0 + acc1) + (acc2 + acc3);
        hv = fast_tanh(xw0 + sum);
        op[0] = hv; op += H;                  // outputs[b,s,t]
        hsh[p ^ 1][t] = (_Float16)hv;         // publish h(s) in back buffer

        lds_barrier();                        // the ONE barrier per step
        p ^= 1;

        xw0 = xw1; xw1 = xwn;
    }
    out[(size_t)B * S * H + (size_t)b * H + t] = hv;   // h_last
}

// ---------------------------------------------------------------------------
extern "C" void kernel_launch(void* const* d_in, const int* in_sizes, int n_in,
                              void* d_out, int out_size, void* d_ws, size_t ws_size,
                              hipStream_t stream) {
    const float* x   = (const float*)d_in[0];
    const float* Wxw = (const float*)d_in[1];
    const float* Wxb = (const float*)d_in[2];
    const float* Whw = (const float*)d_in[3];
    float* out = (float*)d_out;

    dim3 g1(B * S / TM, H / TN);   // 1024 x 4
    phase1_gemm<<<g1, 256, 0, stream>>>(x, Wxw, Wxb, out);
    phase2_rnn<<<B, 256, 0, stream>>>(Whw, out);
}

// Round 3
// 1107.415 us; speedup vs baseline: 1.2657x; 1.2657x over previous
//
#include <hip/hip_runtime.h>

#define B 32
#define S 2048
#define I 256
#define H 256

typedef _Float16 h2 __attribute__((ext_vector_type(2)));

__device__ __forceinline__ float fdot2(h2 a, h2 b, float c) {
#if __has_builtin(__builtin_amdgcn_fdot2)
    return __builtin_amdgcn_fdot2(a, b, c, false);
#else
    return fmaf((float)a[1], (float)b[1], fmaf((float)a[0], (float)b[0], c));
#endif
}

// lgkm-only workgroup barrier: __syncthreads() drains vmcnt(0) before
// s_barrier; our per-step global ops are thread-private columns so only LDS
// needs cross-wave visibility. imm 0xC07F = vmcnt(63) expcnt(7) lgkmcnt(0).
__device__ __forceinline__ void lds_barrier() {
    __asm__ __volatile__("" ::: "memory");
    __builtin_amdgcn_s_waitcnt(0xC07F);
    __builtin_amdgcn_s_barrier();
    __asm__ __volatile__("" ::: "memory");
}

__device__ __forceinline__ float fast_tanh(float x) {
    float e = __expf(2.0f * x);
    return 1.0f - __fdividef(2.0f, e + 1.0f);
}

// quad_perm(1,0,3,2): exchange with lane^1 within each quad
__device__ __forceinline__ float dpp_xor1(float x) {
    return __builtin_bit_cast(float, __builtin_amdgcn_mov_dpp(
        __builtin_bit_cast(int, x), 0xB1, 0xF, 0xF, false));
}
// quad_perm(2,3,0,1): exchange with lane^2 within each quad
__device__ __forceinline__ float dpp_xor2(float x) {
    return __builtin_bit_cast(float, __builtin_amdgcn_mov_dpp(
        __builtin_bit_cast(int, x), 0x4E, 0xF, 0xF, false));
}

// ---------------------------------------------------------------------------
// Phase 1: xw[m][n] = sum_k x[m][k]*Wxw[n][k] + Wxb[n]   (unchanged)
// ---------------------------------------------------------------------------
#define TM 64
#define TN 64
#define TK 32

__global__ __launch_bounds__(256) void phase1_gemm(
    const float* __restrict__ x, const float* __restrict__ Wxw,
    const float* __restrict__ Wxb, float* __restrict__ out)
{
    __shared__ __align__(16) float As[TK][TM + 4];
    __shared__ __align__(16) float Bs[TK][TN + 4];

    const int t  = threadIdx.x;
    const int tn = t & 15, tm = t >> 4;
    const int m0 = blockIdx.x * TM;
    const int n0 = blockIdx.y * TN;

    float acc[4][4] = {};
    float bias[4];
#pragma unroll
    for (int j = 0; j < 4; ++j) bias[j] = Wxb[n0 + 4 * tn + j];

    const int lr = t >> 3;
    const int lc = t & 7;

    for (int kt = 0; kt < I; kt += TK) {
#pragma unroll
        for (int hh = 0; hh < 2; ++hh) {
            const int m = lr + 32 * hh;
            float4 v = *(const float4*)(x   + (size_t)(m0 + m) * I + kt + 4 * lc);
            As[4 * lc + 0][m] = v.x; As[4 * lc + 1][m] = v.y;
            As[4 * lc + 2][m] = v.z; As[4 * lc + 3][m] = v.w;
            float4 w = *(const float4*)(Wxw + (size_t)(n0 + m) * I + kt + 4 * lc);
            Bs[4 * lc + 0][m] = w.x; Bs[4 * lc + 1][m] = w.y;
            Bs[4 * lc + 2][m] = w.z; Bs[4 * lc + 3][m] = w.w;
        }
        __syncthreads();
#pragma unroll
        for (int k = 0; k < TK; ++k) {
            float4 a = *(const float4*)&As[k][4 * tm];
            float4 b = *(const float4*)&Bs[k][4 * tn];
            float av[4] = {a.x, a.y, a.z, a.w};
            float bv[4] = {b.x, b.y, b.z, b.w};
#pragma unroll
            for (int i2 = 0; i2 < 4; ++i2)
#pragma unroll
                for (int j = 0; j < 4; ++j)
                    acc[i2][j] = fmaf(av[i2], bv[j], acc[i2][j]);
        }
        __syncthreads();
    }
#pragma unroll
    for (int i2 = 0; i2 < 4; ++i2) {
        float4 v = { acc[i2][0] + bias[0], acc[i2][1] + bias[1],
                     acc[i2][2] + bias[2], acc[i2][3] + bias[3] };
        *(float4*)(out + (size_t)(m0 + 4 * tm + i2) * H + n0 + 4 * tn) = v;
    }
}

// ---------------------------------------------------------------------------
// Phase 2: h = tanh(xw_s + h @ Whw^T), 2048 steps. 32 blocks x 256 threads.
//
// R7 post-mortem history:
//   - r=1 row/thread (full K): 128 ds_read_b128/CU/step -> LDS-pipe-bound
//     (~11 cyc each ~ 1400 cyc/step). Must keep broadcast count ~32/CU.
//   - r=4 with K split ACROSS WAVES (R3): 32 b128/CU, but cross-wave
//     partial reduce = pbuf round trip + barrier + read latency (~540 stall).
// R7 structure: K split WITHIN each quad of lanes.
//   wave w owns rows [64w, 64w+64). lane l = (j = l>>2, q = l&3) computes
//   rows 64w+4j..+3 over k in [64q, 64q+64): 8 b128 reads/thread (4 distinct
//   addrs/instr, conflict-free via 144B quarter stride), 128 fdot2.
//   Partial reduce: 2-stage DPP quad butterfly (quad_perm 0xB1, 0x4E) --
//   pure VALU, no LDS, no barrier. Lane l lands the full sum for row 64w+l
//   = global row t, matching its xw column and h-write slot.
//   hsh double-buffered; ONE lgkm-only barrier per step publishes h.
// Reduce association (q0+q1)+(q2+q3) == R3's pbuf order -> bit-identical.
// Budget/step: LDS ~390 cyc, VALU issue ~560, one read-latency hop.
// ---------------------------------------------------------------------------
__global__ __launch_bounds__(256, 1) void phase2_rnn(
    const float* __restrict__ Whw, float* __restrict__ out)
{
    // h as f16, 4 k-quarters at 72-element (144 B) stride so the quad's 4
    // concurrent b128 reads hit bank groups 0/4/8/12: conflict-free.
    // Quarter qq holds h[64qq .. 64qq+63] in [0..63]; [64..71] is pad.
    __shared__ __align__(16) _Float16 hsh[2][4][72];

    const int b = blockIdx.x;
    const int t = threadIdx.x;
    const int w = t >> 6;        // wave: rows [64w, 64w+64)
    const int l = t & 63;
    const int j = l >> 2;        // quad: rows 64w+4j .. 64w+4j+3
    const int q = l & 3;         // k-quarter: k in [64q, 64q+64)

    // wreg[i][m] = W[64w+4j+i][64q + 2m .. 2m+1] as h2. Constant indices.
    h2 wreg[4][32];
#pragma unroll
    for (int i = 0; i < 4; ++i) {
        const float4* wp =
            (const float4*)(Whw + (size_t)(64 * w + 4 * j + i) * H + 64 * q);
#pragma unroll
        for (int m = 0; m < 16; ++m) {
            float4 f = wp[m];
            wreg[i][2 * m]     = h2{(_Float16)f.x, (_Float16)f.y};
            wreg[i][2 * m + 1] = h2{(_Float16)f.z, (_Float16)f.w};
        }
    }

    hsh[0][w][l] = (_Float16)0.0f;   // h[t] lives at quarter w, slot l
    __syncthreads();

    // xw column t of batch b, read/written in place in d_out. 2-deep prefetch;
    // reads up to 2 steps past the end land in the h_last region (in bounds,
    // values unused).
    float* outb = out + (size_t)b * S * H + t;
    float*       op = outb;
    const float* lp = outb + 2 * (size_t)H;
    float xw0 = outb[0], xw1 = outb[(size_t)H];

    float hv = 0.f;
    int p = 0;
    for (int s = 0; s < S; ++s) {
        float xwn = lp[0]; lp += H;          // prefetch xw for step s+2

        // MAC: 4 rows x 64 k (own quarter). 8 b128 reads, 128 fdot2.
        const uint4* hp = (const uint4*)&hsh[p][q][0];
        float acc0 = 0.f, acc1 = 0.f, acc2 = 0.f, acc3 = 0.f;
#pragma unroll
        for (int u = 0; u < 8; ++u) {        // uint4 u covers k = 64q+8u ..
            uint4 v = hp[u];
            h2 q0 = __builtin_bit_cast(h2, v.x);
            h2 q1 = __builtin_bit_cast(h2, v.y);
            h2 q2 = __builtin_bit_cast(h2, v.z);
            h2 q3 = __builtin_bit_cast(h2, v.w);
            acc0 = fdot2(wreg[0][4 * u + 0], q0, acc0);
            acc0 = fdot2(wreg[0][4 * u + 1], q1, acc0);
            acc0 = fdot2(wreg[0][4 * u + 2], q2, acc0);
            acc0 = fdot2(wreg[0][4 * u + 3], q3, acc0);
            acc1 = fdot2(wreg[1][4 * u + 0], q0, acc1);
            acc1 = fdot2(wreg[1][4 * u + 1], q1, acc1);
            acc1 = fdot2(wreg[1][4 * u + 2], q2, acc1);
            acc1 = fdot2(wreg[1][4 * u + 3], q3, acc1);
            acc2 = fdot2(wreg[2][4 * u + 0], q0, acc2);
            acc2 = fdot2(wreg[2][4 * u + 1], q1, acc2);
            acc2 = fdot2(wreg[2][4 * u + 2], q2, acc2);
            acc2 = fdot2(wreg[2][4 * u + 3], q3, acc2);
            acc3 = fdot2(wreg[3][4 * u + 0], q0, acc3);
            acc3 = fdot2(wreg[3][4 * u + 1], q1, acc3);
            acc3 = fdot2(wreg[3][4 * u + 2], q2, acc3);
            acc3 = fdot2(wreg[3][4 * u + 3], q3, acc3);
        }

        // Quad butterfly reduce: acc_i = partial of row 4j+i over quarter q.
        // Stage 1 (lane^1): keep rows with i&1 == q&1.
        float X  = (q & 1) ? acc0 : acc1;    // sent
        float Y  = (q & 1) ? acc2 : acc3;
        float U  = (q & 1) ? acc1 : acc0;    // kept
        float V  = (q & 1) ? acc3 : acc2;
        float Sa = U + dpp_xor1(X);          // row (q&1),   k-half {q, q^1}
        float Sb = V + dpp_xor1(Y);          // row 2+(q&1), k-half {q, q^1}
        // Stage 2 (lane^2): keep row with i&2 == q&2 -> final row = q.
        float X2 = (q & 2) ? Sa : Sb;        // sent
        float U2 = (q & 2) ? Sb : Sa;        // kept
        float sum = U2 + dpp_xor2(X2);       // full sum for row 64w+l == t

        hv = fast_tanh(xw0 + sum);
        op[0] = hv; op += H;                  // outputs[b,s,t]
        hsh[p ^ 1][w][l] = (_Float16)hv;      // publish h[t] in back buffer

        lds_barrier();                        // the ONE barrier per step
        p ^= 1;

        xw0 = xw1; xw1 = xwn;
    }
    out[(size_t)B * S * H + (size_t)b * H + t] = hv;   // h_last
}

// ---------------------------------------------------------------------------
extern "C" void kernel_launch(void* const* d_in, const int* in_sizes, int n_in,
                              void* d_out, int out_size, void* d_ws, size_t ws_size,
                              hipStream_t stream) {
    const float* x   = (const float*)d_in[0];
    const float* Wxw = (const float*)d_in[1];
    const float* Wxb = (const float*)d_in[2];
    const float* Whw = (const float*)d_in[3];
    float* out = (float*)d_out;

    dim3 g1(B * S / TM, H / TN);   // 1024 x 4
    phase1_gemm<<<g1, 256, 0, stream>>>(x, Wxw, Wxb, out);
    phase2_rnn<<<B, 256, 0, stream>>>(Whw, out);
}